// Round 7
// baseline (1227.416 us; speedup 1.0000x reference)
//
#include <hip/hip_runtime.h>
#include <cstdint>
#include <cstddef>

#define B_ 32
#define T_ 2048
#define D_ 128
#define U_ 128
#define G4_ 512
#define P1_ROWS 32
#define L2E_ 1.4426950408889634f

typedef _Float16 f16x8 __attribute__((ext_vector_type(8)));
typedef _Float16 f16x2 __attribute__((ext_vector_type(2)));
typedef float f32x4 __attribute__((ext_vector_type(4)));

// LDS-visibility-only barrier (R5-proven): waits this wave's ds ops, syncs the
// block, does NOT drain vmcnt — out[] stores / Zx prefetches stay in flight.
__device__ __forceinline__ void lds_barrier() {
  __builtin_amdgcn_sched_barrier(0);
  asm volatile("s_waitcnt lgkmcnt(0)");
  __builtin_amdgcn_sched_barrier(0);
  __builtin_amdgcn_s_barrier();
  __builtin_amdgcn_sched_barrier(0);
}

// Phase 1: Zx[b][col][t] = s(col) * (bias[col] + sum_k x[b,t,k]*Wx[k][col])
// s(col) = -log2e for i,f,o gates; -2*log2e for g — folds the exp2 scale.
__global__ __launch_bounds__(512)
void zx_kernel(const float* __restrict__ x, const float* __restrict__ Wx,
               const float* __restrict__ bias, float* __restrict__ Zx,
               int tbase, int ct) {
  const int j = threadIdx.x;
  const int nt = ct / P1_ROWS;
  const int tblk = blockIdx.x % nt;
  const int b = blockIdx.x / nt;
  const int t0 = tblk * P1_ROWS;
  const float sj = ((j >> 7) == 2) ? (-2.f * L2E_) : (-L2E_);

  __shared__ float xsT[D_ * P1_ROWS];  // transposed: [k][r]

  const float* xp = x + ((size_t)b * T_ + tbase + t0) * D_;
  {
    int e = j * 8;
    int r = e >> 7;
    int k = e & 127;
    float4 v0 = *(const float4*)(xp + e);
    float4 v1 = *(const float4*)(xp + e + 4);
    xsT[(k + 0) * P1_ROWS + r] = v0.x;
    xsT[(k + 1) * P1_ROWS + r] = v0.y;
    xsT[(k + 2) * P1_ROWS + r] = v0.z;
    xsT[(k + 3) * P1_ROWS + r] = v0.w;
    xsT[(k + 4) * P1_ROWS + r] = v1.x;
    xsT[(k + 5) * P1_ROWS + r] = v1.y;
    xsT[(k + 6) * P1_ROWS + r] = v1.z;
    xsT[(k + 7) * P1_ROWS + r] = v1.w;
  }
  __syncthreads();

  const float bj = bias[j];
  float acc[P1_ROWS];
#pragma unroll
  for (int r = 0; r < P1_ROWS; ++r) acc[r] = bj;

  const float* wp = Wx + j;
  float w = wp[0];
#pragma unroll 2
  for (int k = 0; k < D_; ++k) {
    float wn = (k + 1 < D_) ? wp[(size_t)(k + 1) * G4_] : 0.f;
    const float4* xr = (const float4*)(xsT + k * P1_ROWS);
#pragma unroll
    for (int r4 = 0; r4 < P1_ROWS / 4; ++r4) {
      float4 xv = xr[r4];
      acc[4 * r4 + 0] += xv.x * w;
      acc[4 * r4 + 1] += xv.y * w;
      acc[4 * r4 + 2] += xv.z * w;
      acc[4 * r4 + 3] += xv.w * w;
    }
    w = wn;
  }

  float* zp = Zx + ((size_t)b * G4_ + j) * ct + t0;  // [b][col][t]
#pragma unroll
  for (int q = 0; q < P1_ROWS / 4; ++q)
    ((float4*)zp)[q] = make_float4(sj * acc[4 * q], sj * acc[4 * q + 1],
                                   sj * acc[4 * q + 2], sj * acc[4 * q + 3]);
}

// Phase 2: recurrence via f16 MFMA, depth-1 chains, gate-split activations.
// Wave w owns u in [16w,16w+16); lane = (l4 = lane&15 -> u, kg = lane>>4).
// 16 independent MFMA partials (gate g x k-tile kt) off a persistent zero C.
// Lane activates ONLY gate kg (exp2-folded), then i/f/g/o are exchanged
// in-wave: bpermute(^16) -> f16 pack -> bpermute(^32). Cell update lane-local.
__global__ __launch_bounds__(512)
void lstm_kernel(const float* __restrict__ Zx, const float* __restrict__ Wh,
                 float* __restrict__ out, float* __restrict__ state,
                 int tbase, int ct, int first) {
  const int j = threadIdx.x;
  const int b = blockIdx.x;
  const int w = j >> 6;
  const int lane = j & 63;
  const int l4 = lane & 15;
  const int kg = lane >> 4;       // k-group AND this lane's gate
  const int u = w * 16 + l4;

  const bool evn = (kg & 1) == 0;
  const bool lowg = kg < 2;
  const int idx16 = (lane ^ 16) << 2;
  const int idx32 = (lane ^ 32) << 2;
  const float mk = (kg == 2) ? 2.f : 1.f;    // act = fma(rcp(1+exp2(z')),mk,bk)
  const float bk = (kg == 2) ? -1.f : 0.f;

  // B fragments, scaled by the per-gate exp2 fold
  f16x8 bf[4][4];
#pragma unroll
  for (int g = 0; g < 4; ++g) {
    const float sg = (g == 2) ? (-2.f * L2E_) : (-L2E_);
#pragma unroll
    for (int kt = 0; kt < 4; ++kt) {
      f16x8 v;
#pragma unroll
      for (int e = 0; e < 8; ++e)
        v[e] = (_Float16)(sg * Wh[(size_t)(kt * 32 + kg * 8 + e) * G4_ + g * U_ + u]);
      bf[g][kt] = v;
    }
  }

  __shared__ alignas(16) _Float16 hbuf[2][U_];  // double-buffered h (f16)

  float c_state = 0.f, h0 = 0.f;
  if (!first) {
    h0 = state[b * 2 * U_ + u];
    c_state = state[b * 2 * U_ + U_ + u];
  }
  if (kg == 0) hbuf[0][u] = (_Float16)h0;
  __syncthreads();

  // one Zx column stream per lane: col = kg*U + u
  const float4* zq = (const float4*)(Zx + ((size_t)b * G4_ + kg * U_ + u) * ct);
  float4 zc = zq[0];
  float hlast = h0;
  float* outp = out + ((size_t)tbase * B_ + b) * U_ + u;

  const f32x4 zero4 = {0.f, 0.f, 0.f, 0.f};

  for (int tt = 0; tt < ct; tt += 4) {
    float4 zn = (tt + 4 < ct) ? zq[(tt >> 2) + 1] : make_float4(0.f, 0.f, 0.f, 0.f);
#pragma unroll
    for (int s = 0; s < 4; ++s) {
      const int t = tt + s;
      const int cur = t & 1;
      const float zi = (s == 0) ? zc.x : (s == 1) ? zc.y : (s == 2) ? zc.z : zc.w;

      // A-frags: broadcast h slice per k-group (16B per kt)
      const f16x8* hp = (const f16x8*)hbuf[cur];
      f16x8 a0 = hp[0 * 4 + kg];
      f16x8 a1 = hp[1 * 4 + kg];
      f16x8 a2 = hp[2 * 4 + kg];
      f16x8 a3 = hp[3 * 4 + kg];

      // 16 independent depth-1 MFMAs (gate g, k-tile kt), zero C
      f32x4 c00 = __builtin_amdgcn_mfma_f32_16x16x32_f16(a0, bf[0][0], zero4, 0, 0, 0);
      f32x4 c10 = __builtin_amdgcn_mfma_f32_16x16x32_f16(a0, bf[1][0], zero4, 0, 0, 0);
      f32x4 c20 = __builtin_amdgcn_mfma_f32_16x16x32_f16(a0, bf[2][0], zero4, 0, 0, 0);
      f32x4 c30 = __builtin_amdgcn_mfma_f32_16x16x32_f16(a0, bf[3][0], zero4, 0, 0, 0);
      f32x4 c01 = __builtin_amdgcn_mfma_f32_16x16x32_f16(a1, bf[0][1], zero4, 0, 0, 0);
      f32x4 c11 = __builtin_amdgcn_mfma_f32_16x16x32_f16(a1, bf[1][1], zero4, 0, 0, 0);
      f32x4 c21 = __builtin_amdgcn_mfma_f32_16x16x32_f16(a1, bf[2][1], zero4, 0, 0, 0);
      f32x4 c31 = __builtin_amdgcn_mfma_f32_16x16x32_f16(a1, bf[3][1], zero4, 0, 0, 0);
      f32x4 c02 = __builtin_amdgcn_mfma_f32_16x16x32_f16(a2, bf[0][2], zero4, 0, 0, 0);
      f32x4 c12 = __builtin_amdgcn_mfma_f32_16x16x32_f16(a2, bf[1][2], zero4, 0, 0, 0);
      f32x4 c22 = __builtin_amdgcn_mfma_f32_16x16x32_f16(a2, bf[2][2], zero4, 0, 0, 0);
      f32x4 c32 = __builtin_amdgcn_mfma_f32_16x16x32_f16(a2, bf[3][2], zero4, 0, 0, 0);
      f32x4 c03 = __builtin_amdgcn_mfma_f32_16x16x32_f16(a3, bf[0][3], zero4, 0, 0, 0);
      f32x4 c13 = __builtin_amdgcn_mfma_f32_16x16x32_f16(a3, bf[1][3], zero4, 0, 0, 0);
      f32x4 c23 = __builtin_amdgcn_mfma_f32_16x16x32_f16(a3, bf[2][3], zero4, 0, 0, 0);
      f32x4 c33 = __builtin_amdgcn_mfma_f32_16x16x32_f16(a3, bf[3][3], zero4, 0, 0, 0);

      // per-gate K-sums; lane keeps only its gate's (3 cndmask)
      float z0 = (c00[0] + c01[0]) + (c02[0] + c03[0]);
      float z1 = (c10[0] + c11[0]) + (c12[0] + c13[0]);
      float z2 = (c20[0] + c21[0]) + (c22[0] + c23[0]);
      float z3 = (c30[0] + c31[0]) + (c32[0] + c33[0]);
      float zsel = lowg ? (evn ? z0 : z1) : (evn ? z2 : z3);
      float zs = zsel + zi;  // already exp2-scaled per gate

      // this lane's gate activation only
      float act = fmaf(__builtin_amdgcn_rcpf(1.f + __builtin_amdgcn_exp2f(zs)), mk, bk);

      // in-wave gate exchange: ^16 (f32), pack f16 pair, ^32
      float prt = __builtin_bit_cast(
          float, __builtin_amdgcn_ds_bpermute(idx16, __builtin_bit_cast(int, act)));
      f16x2 spv = __builtin_bit_cast(f16x2, __builtin_amdgcn_cvt_pkrtz(act, prt));
      int oth = __builtin_amdgcn_ds_bpermute(idx32, __builtin_bit_cast(int, spv));
      f16x2 opv = __builtin_bit_cast(f16x2, oth);

      float spl = (float)spv[0], sph = (float)spv[1];
      float opl = (float)opv[0], oph = (float)opv[1];
      float ifl = lowg ? spl : opl, ifh = lowg ? sph : oph;   // {i,f} pair
      float gol = lowg ? opl : spl, goh = lowg ? oph : sph;   // {g,o} pair
      float i_ = evn ? ifl : ifh, f_ = evn ? ifh : ifl;
      float g_ = evn ? gol : goh, o_ = evn ? goh : gol;

      c_state = fmaf(f_, c_state, i_ * g_);
      float tc = fmaf(
          __builtin_amdgcn_rcpf(1.f + __builtin_amdgcn_exp2f(-2.f * L2E_ * c_state)),
          2.f, -1.f);
      float hn = o_ * tc;
      hlast = hn;

      if (kg == 0) {
        outp[(size_t)t * B_ * U_] = hn;
        hbuf[cur ^ 1][u] = (_Float16)hn;
      }
      lds_barrier();  // lgkmcnt(0) + s_barrier; vmem stays in flight
    }
    zc = zn;
  }

  if (kg == 0) {
    state[b * 2 * U_ + u] = hlast;
    state[b * 2 * U_ + U_ + u] = c_state;
  }
}

extern "C" void kernel_launch(void* const* d_in, const int* in_sizes, int n_in,
                              void* d_out, int out_size, void* d_ws, size_t ws_size,
                              hipStream_t stream) {
  const float* x = (const float*)d_in[0];
  const float* Wx = (const float*)d_in[1];
  const float* Wh = (const float*)d_in[2];
  const float* bias = (const float*)d_in[3];
  float* out = (float*)d_out;

  // ws layout: [0,32KB) = h/c carry state, rest = Zx chunk buffer
  float* state = (float*)d_ws;
  float* zx = (float*)((char*)d_ws + 32768);
  size_t avail = ws_size > 32768 ? ws_size - 32768 : 0;
  size_t per_t = (size_t)B_ * G4_ * sizeof(float);  // 64 KB per timestep
  long maxct = (long)(avail / per_t);
  int ct;
  if (maxct >= T_) ct = T_;
  else {
    ct = (int)((maxct / P1_ROWS) * P1_ROWS);
    if (ct < P1_ROWS) ct = P1_ROWS;
  }

  for (int tb = 0; tb < T_; tb += ct) {
    int cur = (T_ - tb < ct) ? (T_ - tb) : ct;
    zx_kernel<<<dim3(B_ * (cur / P1_ROWS)), 512, 0, stream>>>(x, Wx, bias, zx, tb, cur);
    lstm_kernel<<<dim3(B_), 512, 0, stream>>>(zx, Wh, out, state, tb, cur, tb == 0 ? 1 : 0);
  }
}